// Round 1
// baseline (1124.467 us; speedup 1.0000x reference)
//
#include <hip/hip_runtime.h>

#define NODES 16
#define TT    128   // tokens per utterance
#define DIM   256   // local feature dim
#define ATTD  128   // attention inner dim
#define HD    256   // hidden dim (H1 == H2 == 256)
#define NEGV  -1e9f

// ---------------- K1: global Bahdanau attention -> gw[16*16] ----------------
__global__ void k_global_att(const float* __restrict__ G,
                             const float* __restrict__ Wq,
                             const float* __restrict__ Wk,
                             const float* __restrict__ vatt,
                             float* __restrict__ gw) {
  __shared__ float sQ[NODES][ATTD];
  __shared__ float sK[NODES][ATTD];
  __shared__ float sS[NODES][NODES];
  int tid = threadIdx.x;  // 256 threads
  for (int idx = tid; idx < NODES * ATTD; idx += 256) {
    int i = idx / ATTD, a = idx % ATTD;
    float accq = 0.f, acck = 0.f;
    for (int d = 0; d < DIM; ++d) {
      float g = G[i * DIM + d];
      accq = fmaf(g, Wq[d * ATTD + a], accq);
      acck = fmaf(g, Wk[d * ATTD + a], acck);
    }
    sQ[i][a] = accq;
    sK[i][a] = acck;
  }
  __syncthreads();
  {
    int i = tid / NODES, j = tid % NODES;  // tid < 256 == NODES*NODES
    float acc = 0.f;
    for (int a = 0; a < ATTD; ++a)
      acc += tanhf(sQ[i][a] + sK[j][a]) * vatt[a];
    sS[i][j] = acc;
  }
  __syncthreads();
  if (tid < NODES) {
    float m = -1e30f;
    for (int j = 0; j < NODES; ++j) m = fmaxf(m, sS[tid][j]);
    float ex[NODES];
    float sum = 0.f;
    for (int j = 0; j < NODES; ++j) { ex[j] = expf(sS[tid][j] - m); sum += ex[j]; }
    float inv = 1.f / sum;
    for (int j = 0; j < NODES; ++j) gw[tid * NODES + j] = ex[j] * inv;
  }
}

// ---------------- generic 128x128-tile f32 GEMM: C = A[MxK] @ B[KxN] --------
// lda == K, ldb == ldc == Ncols. K % 32 == 0. grid = (M/128, N/128), 256 thr.
template <bool ACC>
__global__ void k_gemm(const float* __restrict__ A,
                       const float* __restrict__ B,
                       float* __restrict__ C,
                       const float* __restrict__ bias,
                       int Ncols, int K) {
  __shared__ float As[32][129];  // As[k][r] (A^T chunk)
  __shared__ float Bs[32][129];  // Bs[k][c]
  int row0 = blockIdx.x * 128;
  int col0 = blockIdx.y * 128;
  int tid = threadIdx.x;
  int tx = tid & 15, ty = tid >> 4;
  float acc[8][8] = {};
  for (int k0 = 0; k0 < K; k0 += 32) {
    for (int idx = tid; idx < 128 * 32; idx += 256) {
      int r = idx >> 5, k = idx & 31;
      As[k][r] = A[(size_t)(row0 + r) * K + (k0 + k)];
    }
    for (int idx = tid; idx < 32 * 128; idx += 256) {
      int k = idx >> 7, c = idx & 127;
      Bs[k][c] = B[(size_t)(k0 + k) * Ncols + (col0 + c)];
    }
    __syncthreads();
#pragma unroll
    for (int k = 0; k < 32; ++k) {
      float a[8], b[8];
#pragma unroll
      for (int u = 0; u < 8; ++u) a[u] = As[k][ty * 8 + u];
#pragma unroll
      for (int v = 0; v < 8; ++v) b[v] = Bs[k][tx * 8 + v];
#pragma unroll
      for (int u = 0; u < 8; ++u)
#pragma unroll
        for (int v = 0; v < 8; ++v)
          acc[u][v] = fmaf(a[u], b[v], acc[u][v]);
    }
    __syncthreads();
  }
#pragma unroll
  for (int u = 0; u < 8; ++u) {
    int r = row0 + ty * 8 + u;
#pragma unroll
    for (int v = 0; v < 8; ++v) {
      int c = col0 + tx * 8 + v;
      size_t o = (size_t)r * Ncols + c;
      if (ACC) C[o] += acc[u][v];
      else     C[o] = acc[u][v] + (bias ? bias[c] : 0.f);
    }
  }
}

// ---------------- K4: Y[i,q] = local[i] @ Wrel1[relid(i,q)] -----------------
// grid = (64, 2): x = i*4+q, y = col tile. Y: [64][128][256]
__global__ void k_y(const float* __restrict__ Lf,
                    const float* __restrict__ Wrel1,
                    const int* __restrict__ speaker,
                    float* __restrict__ Y) {
  __shared__ float As[32][129];
  __shared__ float Bs[32][129];
  int iq = blockIdx.x;
  int i = iq >> 2, q = iq & 3;
  int relid = (speaker[i] * NODES + (q >> 1)) * 2 + (q & 1);
  const float* A = Lf + (size_t)i * TT * DIM;
  const float* B = Wrel1 + (size_t)relid * DIM * HD;
  float* C = Y + (size_t)iq * TT * HD;
  int col0 = blockIdx.y * 128;
  int tid = threadIdx.x;
  int tx = tid & 15, ty = tid >> 4;
  float acc[8][8] = {};
  for (int k0 = 0; k0 < DIM; k0 += 32) {
    for (int idx = tid; idx < 128 * 32; idx += 256) {
      int r = idx >> 5, k = idx & 31;
      As[k][r] = A[(size_t)r * DIM + (k0 + k)];
    }
    for (int idx = tid; idx < 32 * 128; idx += 256) {
      int k = idx >> 7, c = idx & 127;
      Bs[k][c] = B[(size_t)(k0 + k) * HD + (col0 + c)];
    }
    __syncthreads();
#pragma unroll
    for (int k = 0; k < 32; ++k) {
      float a[8], b[8];
#pragma unroll
      for (int u = 0; u < 8; ++u) a[u] = As[k][ty * 8 + u];
#pragma unroll
      for (int v = 0; v < 8; ++v) b[v] = Bs[k][tx * 8 + v];
#pragma unroll
      for (int u = 0; u < 8; ++u)
#pragma unroll
        for (int v = 0; v < 8; ++v)
          acc[u][v] = fmaf(a[u], b[v], acc[u][v]);
    }
    __syncthreads();
  }
#pragma unroll
  for (int u = 0; u < 8; ++u) {
    int r = ty * 8 + u;
#pragma unroll
    for (int v = 0; v < 8; ++v) {
      int c = col0 + tx * 8 + v;
      C[(size_t)r * HD + c] = acc[u][v];
    }
  }
}

// ---------------- K3: local attention per edge -> lw[e][t][s] ---------------
// grid = 256 (one edge), 256 threads. S = P1[i] @ P2[j]^T, mask+softmax.
__global__ void k_locatt(const float* __restrict__ p1,
                         const float* __restrict__ p2,
                         const int* __restrict__ length,
                         float* __restrict__ lw) {
  __shared__ float sP1[TT][ATTD + 1];
  __shared__ float sP2[TT][ATTD + 1];
  __shared__ float sRed[TT][2];
  int e = blockIdx.x;
  int i = e >> 4, j = e & 15;
  int tid = threadIdx.x;
  for (int idx = tid; idx < TT * ATTD; idx += 256) {
    int r = idx >> 7, c = idx & 127;
    sP1[r][c] = p1[(size_t)i * TT * ATTD + idx];
    sP2[r][c] = p2[(size_t)j * TT * ATTD + idx];
  }
  __syncthreads();
  int tx = tid & 15, ty = tid >> 4;
  float acc[8][8] = {};
  for (int a = 0; a < ATTD; ++a) {
    float av[8], bv[8];
#pragma unroll
    for (int u = 0; u < 8; ++u) av[u] = sP1[ty * 8 + u][a];
#pragma unroll
    for (int v = 0; v < 8; ++v) bv[v] = sP2[tx * 8 + v][a];
#pragma unroll
    for (int u = 0; u < 8; ++u)
#pragma unroll
      for (int v = 0; v < 8; ++v)
        acc[u][v] = fmaf(av[u], bv[v], acc[u][v]);
  }
  __syncthreads();           // done reading sP1; reuse as S [128][129]
  float* S = &sP1[0][0];
#pragma unroll
  for (int u = 0; u < 8; ++u)
#pragma unroll
    for (int v = 0; v < 8; ++v)
      S[(size_t)(ty * 8 + u) * 129 + (tx * 8 + v)] = acc[u][v];
  __syncthreads();
  int leni = length[i], lenj = length[j];
  int t = tid & 127, h = tid >> 7;
  int s0 = h * 64;
  float m = -1e30f;
  for (int s = s0; s < s0 + 64; ++s) {
    float vv = (s < lenj) ? S[t * 129 + s] : NEGV;
    m = fmaxf(m, vv);
  }
  sRed[t][h] = m;
  __syncthreads();
  m = fmaxf(sRed[t][0], sRed[t][1]);
  __syncthreads();           // protect sRed before reuse
  float sum = 0.f;
  for (int s = s0; s < s0 + 64; ++s) {
    float vv = (s < lenj) ? S[t * 129 + s] : NEGV;
    float ee = expf(vv - m);
    S[t * 129 + s] = ee;
    sum += ee;
  }
  sRed[t][h] = sum;
  __syncthreads();
  sum = sRed[t][0] + sRed[t][1];
  float scale = (t < leni) ? (1.f / sum) : 0.f;
  size_t base = (size_t)e * TT * TT + (size_t)t * TT;
  for (int s = s0; s < s0 + 64; ++s)
    lw[base + s] = S[t * 129 + s] * scale;
}

// ---------------- K5/K7: weighted transpose-GEMM aggregation ----------------
// part[g][j][s][o] = sum_{i in group g, t} scale_e * lw[e][t][s] * B[bidx][t][o]
// mode 1: scale = gw[e], bidx = i*4 + (spk[j]*2 + (i<j?0:1))  (B = Y)
// mode 2: scale = 1,     bidx = i                              (B = x1)
// grid = (4, 16, 4): (g, j, tile); tile -> s half (64) x o half (128)
__global__ void k_wagg(const float* __restrict__ lw,
                       const float* __restrict__ gw,
                       const float* __restrict__ Bsrc,
                       const int* __restrict__ speaker,
                       float* __restrict__ part,
                       int mode) {
  __shared__ float sA[32][65];    // sA[t][s]
  __shared__ float sB[32][129];   // sB[t][o]
  int g = blockIdx.x, j = blockIdx.y, tile = blockIdx.z;
  int s0 = (tile & 1) * 64;
  int o0 = (tile >> 1) * 128;
  int tid = threadIdx.x;
  int tx = tid & 15, ty = tid >> 4;
  float acc[4][8] = {};
  for (int ii = 0; ii < 4; ++ii) {
    int i = g * 4 + ii;
    int e = i * NODES + j;
    float scale;
    const float* Bp;
    if (mode == 1) {
      scale = gw[e];
      int q = speaker[j] * 2 + ((i < j) ? 0 : 1);
      Bp = Bsrc + (size_t)(i * 4 + q) * TT * HD;
    } else {
      scale = 1.f;
      Bp = Bsrc + (size_t)i * TT * HD;
    }
    const float* lwe = lw + (size_t)e * TT * TT;
    for (int t0 = 0; t0 < TT; t0 += 32) {
      for (int idx = tid; idx < 32 * 64; idx += 256) {
        int k = idx >> 6, ss = idx & 63;
        sA[k][ss] = scale * lwe[(size_t)(t0 + k) * TT + (s0 + ss)];
      }
      for (int idx = tid; idx < 32 * 128; idx += 256) {
        int k = idx >> 7, c = idx & 127;
        sB[k][c] = Bp[(size_t)(t0 + k) * HD + (o0 + c)];
      }
      __syncthreads();
#pragma unroll
      for (int k = 0; k < 32; ++k) {
        float a[4], b[8];
#pragma unroll
        for (int u = 0; u < 4; ++u) a[u] = sA[k][ty * 4 + u];
#pragma unroll
        for (int v = 0; v < 8; ++v) b[v] = sB[k][tx * 8 + v];
#pragma unroll
        for (int u = 0; u < 4; ++u)
#pragma unroll
          for (int v = 0; v < 8; ++v)
            acc[u][v] = fmaf(a[u], b[v], acc[u][v]);
      }
      __syncthreads();
    }
  }
  size_t base = (size_t)(g * NODES + j) * TT * HD;
#pragma unroll
  for (int u = 0; u < 4; ++u) {
    int s = s0 + ty * 4 + u;
#pragma unroll
    for (int v = 0; v < 8; ++v) {
      int o = o0 + tx * 8 + v;
      part[base + (size_t)s * HD + o] = acc[u][v];
    }
  }
}

// ---------------- K6: reduce partials over the 4 source-groups --------------
__global__ void k_reduce(const float* __restrict__ part, float* __restrict__ dst,
                         int addInto) {
  size_t idx = (size_t)blockIdx.x * 256 + threadIdx.x;
  const size_t Q = (size_t)NODES * TT * HD;  // 524288
  float v = part[idx] + part[idx + Q] + part[idx + 2 * Q] + part[idx + 3 * Q];
  if (addInto) dst[idx] += v;
  else         dst[idx] = v;
}

extern "C" void kernel_launch(void* const* d_in, const int* in_sizes, int n_in,
                              void* d_out, int out_size, void* d_ws, size_t ws_size,
                              hipStream_t stream) {
  (void)in_sizes; (void)n_in; (void)out_size; (void)ws_size;
  const float* G      = (const float*)d_in[0];
  const float* Lf     = (const float*)d_in[1];
  const int*   spk    = (const int*)d_in[2];
  const int*   len    = (const int*)d_in[3];
  const float* Wq     = (const float*)d_in[4];
  const float* Wk     = (const float*)d_in[5];
  const float* vatt   = (const float*)d_in[6];
  const float* Wb1    = (const float*)d_in[7];
  const float* Wb2    = (const float*)d_in[8];
  const float* Wrel1  = (const float*)d_in[9];
  const float* Wroot1 = (const float*)d_in[10];
  const float* b1     = (const float*)d_in[11];
  const float* Wrel2  = (const float*)d_in[12];
  const float* Wroot2 = (const float*)d_in[13];
  const float* b2     = (const float*)d_in[14];

  char* ws = (char*)d_ws;
  float* gw   = (float*)(ws);                 // 1 KB
  float* p1   = (float*)(ws + (1ull  << 20)); // 1 MB
  float* p2   = (float*)(ws + (2ull  << 20)); // 1 MB
  float* lw   = (float*)(ws + (3ull  << 20)); // 16 MB
  float* Y    = (float*)(ws + (19ull << 20)); // 8 MB
  float* x1   = (float*)(ws + (27ull << 20)); // 2 MB
  float* part = (float*)(ws + (29ull << 20)); // 8 MB
  float* Z2   = (float*)(ws + (37ull << 20)); // 2 MB
  float* out  = (float*)d_out;

  // 1) global attention weights
  k_global_att<<<1, 256, 0, stream>>>(G, Wq, Wk, vatt, gw);
  // 2-3) local projections p1 = Lf@Wb1, p2 = Lf@Wb2  (M=2048, N=128, K=256)
  k_gemm<false><<<dim3(16, 1), 256, 0, stream>>>(Lf, Wb1, p1, nullptr, 128, 256);
  k_gemm<false><<<dim3(16, 1), 256, 0, stream>>>(Lf, Wb2, p2, nullptr, 128, 256);
  // 4) per-edge local attention -> lw
  k_locatt<<<256, 256, 0, stream>>>(p1, p2, len, lw);
  // 5) Y[i,q] = local[i] @ Wrel1[rel(i,q)]
  k_y<<<dim3(64, 2), 256, 0, stream>>>(Lf, Wrel1, spk, Y);
  // 6) x1 = Lf @ Wroot1 + b1
  k_gemm<false><<<dim3(16, 2), 256, 0, stream>>>(Lf, Wroot1, x1, b1, 256, 256);
  // 7-8) layer-1 aggregation: x1 += sum_i (gw*lw)^T @ Y
  k_wagg<<<dim3(4, 16, 4), 256, 0, stream>>>(lw, gw, Y, spk, part, 1);
  k_reduce<<<2048, 256, 0, stream>>>(part, x1, 1);
  // 9-10) layer-2 pre-aggregation: Z2[j] = sum_i lw^T @ x1[i]
  k_wagg<<<dim3(4, 16, 4), 256, 0, stream>>>(lw, gw, x1, spk, part, 2);
  k_reduce<<<2048, 256, 0, stream>>>(part, Z2, 0);
  // 11-12) out = Z2 @ Wrel2 + b2 + x1 @ Wroot2
  k_gemm<false><<<dim3(16, 2), 256, 0, stream>>>(Z2, Wrel2, out, b2, 256, 256);
  k_gemm<true ><<<dim3(16, 2), 256, 0, stream>>>(x1, Wroot2, out, nullptr, 256, 256);
}

// Round 2
// 742.392 us; speedup vs baseline: 1.5147x; 1.5147x over previous
//
#include <hip/hip_runtime.h>

#define NODES 16
#define TT    128   // tokens per utterance
#define DIM   256   // local feature dim
#define ATTD  128   // attention inner dim
#define HD    256   // hidden dim (H1 == H2 == 256)
#define NEGV  -1e9f

// ---------------- K1: global Bahdanau attention -> gw[16*16] ----------------
__global__ void k_global_att(const float* __restrict__ G,
                             const float* __restrict__ Wq,
                             const float* __restrict__ Wk,
                             const float* __restrict__ vatt,
                             float* __restrict__ gw) {
  __shared__ float sQ[NODES][ATTD];
  __shared__ float sK[NODES][ATTD];
  __shared__ float sS[NODES][NODES];
  int tid = threadIdx.x;  // 256 threads
  for (int idx = tid; idx < NODES * ATTD; idx += 256) {
    int i = idx / ATTD, a = idx % ATTD;
    float accq = 0.f, acck = 0.f;
    for (int d = 0; d < DIM; ++d) {
      float g = G[i * DIM + d];
      accq = fmaf(g, Wq[d * ATTD + a], accq);
      acck = fmaf(g, Wk[d * ATTD + a], acck);
    }
    sQ[i][a] = accq;
    sK[i][a] = acck;
  }
  __syncthreads();
  {
    int i = tid / NODES, j = tid % NODES;  // tid < 256 == NODES*NODES
    float acc = 0.f;
    for (int a = 0; a < ATTD; ++a)
      acc += tanhf(sQ[i][a] + sK[j][a]) * vatt[a];
    sS[i][j] = acc;
  }
  __syncthreads();
  if (tid < NODES) {
    float m = -1e30f;
    for (int j = 0; j < NODES; ++j) m = fmaxf(m, sS[tid][j]);
    float ex[NODES];
    float sum = 0.f;
    for (int j = 0; j < NODES; ++j) { ex[j] = expf(sS[tid][j] - m); sum += ex[j]; }
    float inv = 1.f / sum;
    for (int j = 0; j < NODES; ++j) gw[tid * NODES + j] = ex[j] * inv;
  }
}

// ---------------- generic 128x128-tile f32 GEMM: C = A[MxK] @ B[KxN] --------
// lda == K, ldb == ldc == Ncols. K % 32 == 0. grid = (M/128, N/128, nPair).
// blockIdx.z == 1 uses (Bb, Cb) instead of (B, C) — lets p1/p2 share a launch.
template <bool ACC>
__global__ __launch_bounds__(256, 1)
void k_gemm(const float* __restrict__ A,
            const float* __restrict__ B,
            float* __restrict__ C,
            const float* __restrict__ Bb,
            float* __restrict__ Cb,
            const float* __restrict__ bias,
            int Ncols, int K) {
  __shared__ float As[32][129];  // As[k][r] (A^T chunk)
  __shared__ float Bs[32][129];  // Bs[k][c]
  if (blockIdx.z == 1) { B = Bb; C = Cb; }
  int row0 = blockIdx.x * 128;
  int col0 = blockIdx.y * 128;
  int tid = threadIdx.x;
  int tx = tid & 15, ty = tid >> 4;
  float acc[8][8] = {};
  for (int k0 = 0; k0 < K; k0 += 32) {
    for (int idx = tid; idx < 128 * 32; idx += 256) {
      int r = idx >> 5, k = idx & 31;
      As[k][r] = A[(size_t)(row0 + r) * K + (k0 + k)];
    }
    for (int idx = tid; idx < 32 * 128; idx += 256) {
      int k = idx >> 7, c = idx & 127;
      Bs[k][c] = B[(size_t)(k0 + k) * Ncols + (col0 + c)];
    }
    __syncthreads();
#pragma unroll
    for (int k = 0; k < 32; ++k) {
      float a[8], b[8];
#pragma unroll
      for (int u = 0; u < 8; ++u) a[u] = As[k][ty * 8 + u];
#pragma unroll
      for (int v = 0; v < 8; ++v) b[v] = Bs[k][tx * 8 + v];
#pragma unroll
      for (int u = 0; u < 8; ++u)
#pragma unroll
        for (int v = 0; v < 8; ++v)
          acc[u][v] = fmaf(a[u], b[v], acc[u][v]);
    }
    __syncthreads();
  }
#pragma unroll
  for (int u = 0; u < 8; ++u) {
    int r = row0 + ty * 8 + u;
#pragma unroll
    for (int v = 0; v < 8; ++v) {
      int c = col0 + tx * 8 + v;
      size_t o = (size_t)r * Ncols + c;
      if (ACC) C[o] += acc[u][v];
      else     C[o] = acc[u][v] + (bias ? bias[c] : 0.f);
    }
  }
}

// -------- fused final GEMM: C = A1@B1 + A2@B2 + bias  (both K=256) ----------
__global__ __launch_bounds__(256, 1)
void k_gemm2(const float* __restrict__ A1, const float* __restrict__ B1,
             const float* __restrict__ A2, const float* __restrict__ B2,
             const float* __restrict__ bias, float* __restrict__ C,
             int Ncols, int K) {
  __shared__ float As[32][129];
  __shared__ float Bs[32][129];
  int row0 = blockIdx.x * 128;
  int col0 = blockIdx.y * 128;
  int tid = threadIdx.x;
  int tx = tid & 15, ty = tid >> 4;
  float acc[8][8] = {};
  for (int src = 0; src < 2; ++src) {
    const float* A = src ? A2 : A1;
    const float* B = src ? B2 : B1;
    for (int k0 = 0; k0 < K; k0 += 32) {
      for (int idx = tid; idx < 128 * 32; idx += 256) {
        int r = idx >> 5, k = idx & 31;
        As[k][r] = A[(size_t)(row0 + r) * K + (k0 + k)];
      }
      for (int idx = tid; idx < 32 * 128; idx += 256) {
        int k = idx >> 7, c = idx & 127;
        Bs[k][c] = B[(size_t)(k0 + k) * Ncols + (col0 + c)];
      }
      __syncthreads();
#pragma unroll
      for (int k = 0; k < 32; ++k) {
        float a[8], b[8];
#pragma unroll
        for (int u = 0; u < 8; ++u) a[u] = As[k][ty * 8 + u];
#pragma unroll
        for (int v = 0; v < 8; ++v) b[v] = Bs[k][tx * 8 + v];
#pragma unroll
        for (int u = 0; u < 8; ++u)
#pragma unroll
          for (int v = 0; v < 8; ++v)
            acc[u][v] = fmaf(a[u], b[v], acc[u][v]);
      }
      __syncthreads();
    }
  }
#pragma unroll
  for (int u = 0; u < 8; ++u) {
    int r = row0 + ty * 8 + u;
#pragma unroll
    for (int v = 0; v < 8; ++v) {
      int c = col0 + tx * 8 + v;
      C[(size_t)r * Ncols + c] = acc[u][v] + bias[c];
    }
  }
}

// ---------------- K4: Y[i,q] = local[i] @ Wrel1[relid(i,q)] -----------------
// grid = (64, 2): x = i*4+q, y = col tile. Y: [64][128][256]
__global__ __launch_bounds__(256, 1)
void k_y(const float* __restrict__ Lf,
         const float* __restrict__ Wrel1,
         const int* __restrict__ speaker,
         float* __restrict__ Y) {
  __shared__ float As[32][129];
  __shared__ float Bs[32][129];
  int iq = blockIdx.x;
  int i = iq >> 2, q = iq & 3;
  int relid = (speaker[i] * NODES + (q >> 1)) * 2 + (q & 1);
  const float* A = Lf + (size_t)i * TT * DIM;
  const float* B = Wrel1 + (size_t)relid * DIM * HD;
  float* C = Y + (size_t)iq * TT * HD;
  int col0 = blockIdx.y * 128;
  int tid = threadIdx.x;
  int tx = tid & 15, ty = tid >> 4;
  float acc[8][8] = {};
  for (int k0 = 0; k0 < DIM; k0 += 32) {
    for (int idx = tid; idx < 128 * 32; idx += 256) {
      int r = idx >> 5, k = idx & 31;
      As[k][r] = A[(size_t)r * DIM + (k0 + k)];
    }
    for (int idx = tid; idx < 32 * 128; idx += 256) {
      int k = idx >> 7, c = idx & 127;
      Bs[k][c] = B[(size_t)(k0 + k) * HD + (col0 + c)];
    }
    __syncthreads();
#pragma unroll
    for (int k = 0; k < 32; ++k) {
      float a[8], b[8];
#pragma unroll
      for (int u = 0; u < 8; ++u) a[u] = As[k][ty * 8 + u];
#pragma unroll
      for (int v = 0; v < 8; ++v) b[v] = Bs[k][tx * 8 + v];
#pragma unroll
      for (int u = 0; u < 8; ++u)
#pragma unroll
        for (int v = 0; v < 8; ++v)
          acc[u][v] = fmaf(a[u], b[v], acc[u][v]);
    }
    __syncthreads();
  }
#pragma unroll
  for (int u = 0; u < 8; ++u) {
    int r = ty * 8 + u;
#pragma unroll
    for (int v = 0; v < 8; ++v) {
      int c = col0 + tx * 8 + v;
      C[(size_t)r * HD + c] = acc[u][v];
    }
  }
}

// ---------------- K3: local attention per edge -> lw[e][t][s] ---------------
// grid = 256 (one edge), 256 threads. S = P1[i] @ P2[j]^T, mask+softmax.
__global__ __launch_bounds__(256, 1)
void k_locatt(const float* __restrict__ p1,
              const float* __restrict__ p2,
              const int* __restrict__ length,
              float* __restrict__ lw) {
  __shared__ float sP1[TT][ATTD + 1];
  __shared__ float sP2[TT][ATTD + 1];
  __shared__ float sRed[TT][2];
  int e = blockIdx.x;
  int i = e >> 4, j = e & 15;
  int tid = threadIdx.x;
  for (int idx = tid; idx < TT * ATTD; idx += 256) {
    int r = idx >> 7, c = idx & 127;
    sP1[r][c] = p1[(size_t)i * TT * ATTD + idx];
    sP2[r][c] = p2[(size_t)j * TT * ATTD + idx];
  }
  __syncthreads();
  int tx = tid & 15, ty = tid >> 4;
  float acc[8][8] = {};
  for (int a = 0; a < ATTD; ++a) {
    float av[8], bv[8];
#pragma unroll
    for (int u = 0; u < 8; ++u) av[u] = sP1[ty * 8 + u][a];
#pragma unroll
    for (int v = 0; v < 8; ++v) bv[v] = sP2[tx * 8 + v][a];
#pragma unroll
    for (int u = 0; u < 8; ++u)
#pragma unroll
      for (int v = 0; v < 8; ++v)
        acc[u][v] = fmaf(av[u], bv[v], acc[u][v]);
  }
  __syncthreads();           // done reading sP1; reuse as S [128][129]
  float* S = &sP1[0][0];
#pragma unroll
  for (int u = 0; u < 8; ++u)
#pragma unroll
    for (int v = 0; v < 8; ++v)
      S[(size_t)(ty * 8 + u) * 129 + (tx * 8 + v)] = acc[u][v];
  __syncthreads();
  int leni = length[i], lenj = length[j];
  int t = tid & 127, h = tid >> 7;
  int s0 = h * 64;
  float m = -1e30f;
  for (int s = s0; s < s0 + 64; ++s) {
    float vv = (s < lenj) ? S[t * 129 + s] : NEGV;
    m = fmaxf(m, vv);
  }
  sRed[t][h] = m;
  __syncthreads();
  m = fmaxf(sRed[t][0], sRed[t][1]);
  __syncthreads();           // protect sRed before reuse
  float sum = 0.f;
  for (int s = s0; s < s0 + 64; ++s) {
    float vv = (s < lenj) ? S[t * 129 + s] : NEGV;
    float ee = expf(vv - m);
    S[t * 129 + s] = ee;
    sum += ee;
  }
  sRed[t][h] = sum;
  __syncthreads();
  sum = sRed[t][0] + sRed[t][1];
  float scale = (t < leni) ? (1.f / sum) : 0.f;
  size_t base = (size_t)e * TT * TT + (size_t)t * TT;
  for (int s = s0; s < s0 + 64; ++s)
    lw[base + s] = S[t * 129 + s] * scale;
}

// ---------------- K5/K7: weighted transpose-GEMM aggregation ----------------
// part[g][j][s][o] = sum_{i in group g, t} scale_e * lw[e][t][s] * B[bidx][t][o]
// mode 1: scale = gw[e], bidx = i*4 + (spk[j]*2 + (i<j?0:1))  (B = Y)
// mode 2: scale = 1,     bidx = i                              (B = x1)
// grid = (4, 16, 4): (g, j, tile); tile -> s half (64) x o half (128)
__global__ __launch_bounds__(256, 1)
void k_wagg(const float* __restrict__ lw,
            const float* __restrict__ gw,
            const float* __restrict__ Bsrc,
            const int* __restrict__ speaker,
            float* __restrict__ part,
            int mode) {
  __shared__ float sA[32][65];    // sA[t][s]
  __shared__ float sB[32][129];   // sB[t][o]
  int g = blockIdx.x, j = blockIdx.y, tile = blockIdx.z;
  int s0 = (tile & 1) * 64;
  int o0 = (tile >> 1) * 128;
  int tid = threadIdx.x;
  int tx = tid & 15, ty = tid >> 4;
  float acc[4][8] = {};
  for (int ii = 0; ii < 4; ++ii) {
    int i = g * 4 + ii;
    int e = i * NODES + j;
    float scale;
    const float* Bp;
    if (mode == 1) {
      scale = gw[e];
      int q = speaker[j] * 2 + ((i < j) ? 0 : 1);
      Bp = Bsrc + (size_t)(i * 4 + q) * TT * HD;
    } else {
      scale = 1.f;
      Bp = Bsrc + (size_t)i * TT * HD;
    }
    const float* lwe = lw + (size_t)e * TT * TT;
    for (int t0 = 0; t0 < TT; t0 += 32) {
      for (int idx = tid; idx < 32 * 64; idx += 256) {
        int k = idx >> 6, ss = idx & 63;
        sA[k][ss] = scale * lwe[(size_t)(t0 + k) * TT + (s0 + ss)];
      }
      for (int idx = tid; idx < 32 * 128; idx += 256) {
        int k = idx >> 7, c = idx & 127;
        sB[k][c] = Bp[(size_t)(t0 + k) * HD + (o0 + c)];
      }
      __syncthreads();
#pragma unroll
      for (int k = 0; k < 32; ++k) {
        float a[4], b[8];
#pragma unroll
        for (int u = 0; u < 4; ++u) a[u] = sA[k][ty * 4 + u];
#pragma unroll
        for (int v = 0; v < 8; ++v) b[v] = sB[k][tx * 8 + v];
#pragma unroll
        for (int u = 0; u < 4; ++u)
#pragma unroll
          for (int v = 0; v < 8; ++v)
            acc[u][v] = fmaf(a[u], b[v], acc[u][v]);
      }
      __syncthreads();
    }
  }
  size_t base = (size_t)(g * NODES + j) * TT * HD;
#pragma unroll
  for (int u = 0; u < 4; ++u) {
    int s = s0 + ty * 4 + u;
#pragma unroll
    for (int v = 0; v < 8; ++v) {
      int o = o0 + tx * 8 + v;
      part[base + (size_t)s * HD + o] = acc[u][v];
    }
  }
}

// ---------------- K6: reduce partials over the 4 source-groups --------------
__global__ void k_reduce(const float* __restrict__ part, float* __restrict__ dst,
                         int addInto) {
  size_t idx = (size_t)blockIdx.x * 256 + threadIdx.x;
  const size_t Q = (size_t)NODES * TT * HD;  // 524288
  float v = part[idx] + part[idx + Q] + part[idx + 2 * Q] + part[idx + 3 * Q];
  if (addInto) dst[idx] += v;
  else         dst[idx] = v;
}

extern "C" void kernel_launch(void* const* d_in, const int* in_sizes, int n_in,
                              void* d_out, int out_size, void* d_ws, size_t ws_size,
                              hipStream_t stream) {
  (void)in_sizes; (void)n_in; (void)out_size; (void)ws_size;
  const float* G      = (const float*)d_in[0];
  const float* Lf     = (const float*)d_in[1];
  const int*   spk    = (const int*)d_in[2];
  const int*   len    = (const int*)d_in[3];
  const float* Wq     = (const float*)d_in[4];
  const float* Wk     = (const float*)d_in[5];
  const float* vatt   = (const float*)d_in[6];
  const float* Wb1    = (const float*)d_in[7];
  const float* Wb2    = (const float*)d_in[8];
  const float* Wrel1  = (const float*)d_in[9];
  const float* Wroot1 = (const float*)d_in[10];
  const float* b1     = (const float*)d_in[11];
  const float* Wrel2  = (const float*)d_in[12];
  const float* Wroot2 = (const float*)d_in[13];
  const float* b2     = (const float*)d_in[14];

  char* ws = (char*)d_ws;
  float* gw   = (float*)(ws);                 // 1 KB
  float* p1   = (float*)(ws + (1ull  << 20)); // 1 MB
  float* p2   = (float*)(ws + (2ull  << 20)); // 1 MB
  float* lw   = (float*)(ws + (3ull  << 20)); // 16 MB
  float* Y    = (float*)(ws + (19ull << 20)); // 8 MB
  float* x1   = (float*)(ws + (27ull << 20)); // 2 MB
  float* part = (float*)(ws + (29ull << 20)); // 8 MB
  float* Z2   = (float*)(ws + (37ull << 20)); // 2 MB
  float* out  = (float*)d_out;

  // 1) global attention weights
  k_global_att<<<1, 256, 0, stream>>>(G, Wq, Wk, vatt, gw);
  // 2) local projections p1 = Lf@Wb1, p2 = Lf@Wb2 in one launch (z selects)
  k_gemm<false><<<dim3(16, 1, 2), 256, 0, stream>>>(Lf, Wb1, p1, Wb2, p2,
                                                    nullptr, 128, 256);
  // 3) per-edge local attention -> lw
  k_locatt<<<256, 256, 0, stream>>>(p1, p2, len, lw);
  // 4) Y[i,q] = local[i] @ Wrel1[rel(i,q)]
  k_y<<<dim3(64, 2), 256, 0, stream>>>(Lf, Wrel1, spk, Y);
  // 5) x1 = Lf @ Wroot1 + b1
  k_gemm<false><<<dim3(16, 2, 1), 256, 0, stream>>>(Lf, Wroot1, x1, nullptr,
                                                    nullptr, b1, 256, 256);
  // 6-7) layer-1 aggregation: x1 += sum_i (gw*lw)^T @ Y
  k_wagg<<<dim3(4, 16, 4), 256, 0, stream>>>(lw, gw, Y, spk, part, 1);
  k_reduce<<<2048, 256, 0, stream>>>(part, x1, 1);
  // 8-9) layer-2 pre-aggregation: Z2[j] = sum_i lw^T @ x1[i]
  k_wagg<<<dim3(4, 16, 4), 256, 0, stream>>>(lw, gw, x1, spk, part, 2);
  k_reduce<<<2048, 256, 0, stream>>>(part, Z2, 0);
  // 10) out = Z2 @ Wrel2 + x1 @ Wroot2 + b2 (fused)
  k_gemm2<<<dim3(16, 2), 256, 0, stream>>>(Z2, Wrel2, x1, Wroot2, b2, out,
                                           256, 256);
}

// Round 3
// 205.994 us; speedup vs baseline: 5.4587x; 3.6040x over previous
//
#include <hip/hip_runtime.h>

#define NODES 16
#define TT    128   // tokens per utterance
#define DIM   256   // local feature dim
#define ATTD  128   // attention inner dim
#define HD    256   // hidden dim
#define NEGV  -1e9f

typedef short bf16x8 __attribute__((ext_vector_type(8)));
typedef float f32x4  __attribute__((ext_vector_type(4)));
typedef unsigned short ushort_t;
typedef ushort_t u16x4 __attribute__((ext_vector_type(4)));
typedef ushort_t u16x8 __attribute__((ext_vector_type(8)));

__device__ __forceinline__ ushort_t f2b(float f) {
  union { float f; unsigned u; } v; v.f = f;
  unsigned r = (v.u + 0x7fffu + ((v.u >> 16) & 1u)) >> 16;
  return (ushort_t)r;
}

// one K=32 step of a 64x64 wave-tile GEMM; A row-major [.,as], BT row-major [.,bs]
__device__ __forceinline__ void wave_gemm_step(const ushort_t* __restrict__ A, int as, int R0,
                                               const ushort_t* __restrict__ BT, int bs, int C0,
                                               int kb, int lr, f32x4 acc[4][4]) {
  bf16x8 a[4], b[4];
#pragma unroll
  for (int m = 0; m < 4; ++m)
    a[m] = *(const bf16x8*)(A + (size_t)(R0 + m * 16 + lr) * as + kb);
#pragma unroll
  for (int n = 0; n < 4; ++n)
    b[n] = *(const bf16x8*)(BT + (size_t)(C0 + n * 16 + lr) * bs + kb);
#pragma unroll
  for (int m = 0; m < 4; ++m)
#pragma unroll
    for (int n = 0; n < 4; ++n)
      acc[m][n] = __builtin_amdgcn_mfma_f32_16x16x32_bf16(a[m], b[n], acc[m][n], 0, 0, 0);
}

#define WAVE_SETUP                                    \
  int tid = threadIdx.x;                              \
  int wave = tid >> 6, lane = tid & 63;               \
  int wr = wave >> 1, wc = wave & 1;                  \
  int lr = lane & 15, kg = lane >> 4;                 \
  (void)wr; (void)wc;

#define ACC_INIT(acc)                                 \
  f32x4 acc[4][4];                                    \
  { f32x4 z = {0.f, 0.f, 0.f, 0.f};                   \
    _Pragma("unroll") for (int m = 0; m < 4; ++m)     \
    _Pragma("unroll") for (int n = 0; n < 4; ++n) acc[m][n] = z; }

// ---------------- prep: cast local_features to bf16 -------------------------
__global__ void k_cast_lf(const float* __restrict__ Lf, ushort_t* __restrict__ Lfh) {
  int gi = blockIdx.x * 256 + threadIdx.x;  // 65536 threads x 8 elems
  const float4* src = (const float4*)Lf;
  float4 v0 = src[gi * 2], v1 = src[gi * 2 + 1];
  u16x8 o;
  o[0] = f2b(v0.x); o[1] = f2b(v0.y); o[2] = f2b(v0.z); o[3] = f2b(v0.w);
  o[4] = f2b(v1.x); o[5] = f2b(v1.y); o[6] = f2b(v1.z); o[7] = f2b(v1.w);
  *(u16x8*)(Lfh + (size_t)gi * 8) = o;
}

// ---------------- prep: cast+transpose all weight matrices ------------------
// grid = 192 blocks; 64x64 tiles through LDS.
__global__ void k_transW(const float* __restrict__ Wb1, const float* __restrict__ Wb2,
                         const float* __restrict__ Wroot1, const float* __restrict__ Wroot2,
                         const float* __restrict__ Wrel2, const float* __restrict__ Wrel1,
                         ushort_t* __restrict__ Wb1T, ushort_t* __restrict__ Wb2T,
                         ushort_t* __restrict__ Wroot1T, ushort_t* __restrict__ Wroot2T,
                         ushort_t* __restrict__ Wrel2T, ushort_t* __restrict__ Wrel1T8) {
  __shared__ float lds[64][65];
  int b = blockIdx.x;
  const float* src; ushort_t* dst; int R, C, t;
  if (b < 8)       { src = Wb1;    dst = Wb1T;    R = 256; C = 128; t = b; }
  else if (b < 16) { src = Wb2;    dst = Wb2T;    R = 256; C = 128; t = b - 8; }
  else if (b < 32) { src = Wroot1; dst = Wroot1T; R = 256; C = 256; t = b - 16; }
  else if (b < 48) { src = Wroot2; dst = Wroot2T; R = 256; C = 256; t = b - 32; }
  else if (b < 64) { src = Wrel2;  dst = Wrel2T;  R = 256; C = 256; t = b - 48; }
  else {
    int m = (b - 64) >> 4;                 // 0..7 -> spk_i*4 + q
    int relid = (m >> 2) * 32 + (m & 3);   // (spk_i*16 + spk_j)*2 + dir
    src = Wrel1 + (size_t)relid * 65536;
    dst = Wrel1T8 + (size_t)m * 65536;
    R = 256; C = 256; t = (b - 64) & 15;
  }
  int tilesC = C >> 6;
  int r0 = (t / tilesC) * 64, c0 = (t % tilesC) * 64;
  int tid = threadIdx.x;
  for (int p = 0; p < 16; ++p) {
    int idx = p * 256 + tid, rr = idx >> 6, cc = idx & 63;
    lds[rr][cc] = src[(size_t)(r0 + rr) * C + c0 + cc];
  }
  __syncthreads();
  for (int p = 0; p < 16; ++p) {
    int idx = p * 256 + tid, rr = idx >> 6, cc = idx & 63;
    dst[(size_t)(c0 + rr) * R + r0 + cc] = f2b(lds[cc][rr]);
  }
}

// ---------------- global Bahdanau attention -> gw[256] (f32) ----------------
__global__ void k_global_att(const float* __restrict__ G,
                             const float* __restrict__ Wq,
                             const float* __restrict__ Wk,
                             const float* __restrict__ vatt,
                             float* __restrict__ gw) {
  __shared__ float sQ[NODES][ATTD];
  __shared__ float sK[NODES][ATTD];
  __shared__ float sS[NODES][NODES];
  int tid = threadIdx.x;
  for (int idx = tid; idx < NODES * ATTD; idx += 256) {
    int i = idx / ATTD, a = idx % ATTD;
    float accq = 0.f, acck = 0.f;
    for (int d = 0; d < DIM; ++d) {
      float g = G[i * DIM + d];
      accq = fmaf(g, Wq[d * ATTD + a], accq);
      acck = fmaf(g, Wk[d * ATTD + a], acck);
    }
    sQ[i][a] = accq;
    sK[i][a] = acck;
  }
  __syncthreads();
  {
    int i = tid / NODES, j = tid % NODES;
    float acc = 0.f;
    for (int a = 0; a < ATTD; ++a)
      acc += tanhf(sQ[i][a] + sK[j][a]) * vatt[a];
    sS[i][j] = acc;
  }
  __syncthreads();
  if (tid < NODES) {
    float m = -1e30f;
    for (int j = 0; j < NODES; ++j) m = fmaxf(m, sS[tid][j]);
    float ex[NODES];
    float sum = 0.f;
    for (int j = 0; j < NODES; ++j) { ex[j] = expf(sS[tid][j] - m); sum += ex[j]; }
    float inv = 1.f / sum;
    for (int j = 0; j < NODES; ++j) gw[tid * NODES + j] = ex[j] * inv;
  }
}

// ---------------- p1/p2 = Lfh @ Wb{1,2}  -> bf16 [2048][128] ----------------
// grid = (16, 2): y selects which projection.
__global__ __launch_bounds__(256, 1)
void k_proj(const ushort_t* __restrict__ Lfh, const ushort_t* __restrict__ Wb1T,
            const ushort_t* __restrict__ Wb2T, ushort_t* __restrict__ p1h,
            ushort_t* __restrict__ p2h) {
  const ushort_t* BT = blockIdx.y ? Wb2T : Wb1T;
  ushort_t* out = blockIdx.y ? p2h : p1h;
  WAVE_SETUP
  int R0 = blockIdx.x * 128 + wr * 64, C0 = wc * 64;
  ACC_INIT(acc)
  for (int kk = 0; kk < 8; ++kk)
    wave_gemm_step(Lfh, DIM, R0, BT, DIM, C0, kk * 32 + kg * 8, lr, acc);
#pragma unroll
  for (int m = 0; m < 4; ++m)
#pragma unroll
    for (int n = 0; n < 4; ++n) {
      int col = C0 + n * 16 + lr;
#pragma unroll
      for (int r = 0; r < 4; ++r) {
        int row = R0 + m * 16 + kg * 4 + r;
        out[(size_t)row * ATTD + col] = f2b(acc[m][n][r]);
      }
    }
}

// ---------------- x1part = Lfh @ Wroot1 + b1 -> f32 [2048][256] -------------
__global__ __launch_bounds__(256, 1)
void k_x1root(const ushort_t* __restrict__ Lfh, const ushort_t* __restrict__ Wroot1T,
              const float* __restrict__ b1, float* __restrict__ x1part) {
  WAVE_SETUP
  int R0 = blockIdx.x * 128 + wr * 64, C0 = blockIdx.y * 128 + wc * 64;
  ACC_INIT(acc)
  for (int kk = 0; kk < 8; ++kk)
    wave_gemm_step(Lfh, DIM, R0, Wroot1T, DIM, C0, kk * 32 + kg * 8, lr, acc);
#pragma unroll
  for (int m = 0; m < 4; ++m)
#pragma unroll
    for (int n = 0; n < 4; ++n) {
      int col = C0 + n * 16 + lr;
      float bb = b1[col];
#pragma unroll
      for (int r = 0; r < 4; ++r) {
        int row = R0 + m * 16 + kg * 4 + r;
        x1part[(size_t)row * HD + col] = acc[m][n][r] + bb;
      }
    }
}

// ---------------- YT[iq][o][t] = (Lfh[i] @ Wrel1[rel])^T, bf16 --------------
// grid = (64, 2)
__global__ __launch_bounds__(256, 1)
void k_y(const ushort_t* __restrict__ Lfh, const ushort_t* __restrict__ Wrel1T8,
         const int* __restrict__ spk, ushort_t* __restrict__ YT) {
  int iq = blockIdx.x;
  int i = iq >> 2, q = iq & 3;
  int m8 = spk[i] * 4 + q;
  const ushort_t* A  = Lfh + (size_t)i * TT * DIM;
  const ushort_t* BT = Wrel1T8 + (size_t)m8 * 65536;
  WAVE_SETUP
  int R0 = wr * 64, C0 = blockIdx.y * 128 + wc * 64;
  ACC_INIT(acc)
  for (int kk = 0; kk < 8; ++kk)
    wave_gemm_step(A, DIM, R0, BT, DIM, C0, kk * 32 + kg * 8, lr, acc);
#pragma unroll
  for (int m = 0; m < 4; ++m)
#pragma unroll
    for (int n = 0; n < 4; ++n) {
      int o = C0 + n * 16 + lr;
      int t0 = R0 + m * 16 + kg * 4;
      u16x4 v;
#pragma unroll
      for (int r = 0; r < 4; ++r) v[r] = f2b(acc[m][n][r]);
      *(u16x4*)(YT + (size_t)iq * 32768 + (size_t)o * TT + t0) = v;
    }
}

// ---------------- per-edge local attention -> lwT, lwgT (bf16) --------------
// grid = 256 blocks (one per edge)
__global__ __launch_bounds__(256, 1)
void k_locatt(const ushort_t* __restrict__ p1h, const ushort_t* __restrict__ p2h,
              const int* __restrict__ length, const float* __restrict__ gw,
              ushort_t* __restrict__ lwT, ushort_t* __restrict__ lwgT) {
  __shared__ float S[TT][130];
  __shared__ float red[TT][2];
  __shared__ float sInv[TT];
  int e = blockIdx.x, i = e >> 4, j = e & 15;
  WAVE_SETUP
  int R0 = wr * 64, C0 = wc * 64;
  const ushort_t* A = p1h + (size_t)i * TT * ATTD;
  const ushort_t* B = p2h + (size_t)j * TT * ATTD;  // BT of p2^T is p2 itself
  ACC_INIT(acc)
  for (int kk = 0; kk < 4; ++kk)
    wave_gemm_step(A, ATTD, R0, B, ATTD, C0, kk * 32 + kg * 8, lr, acc);
#pragma unroll
  for (int m = 0; m < 4; ++m)
#pragma unroll
    for (int n = 0; n < 4; ++n)
#pragma unroll
      for (int r = 0; r < 4; ++r)
        S[R0 + m * 16 + kg * 4 + r][C0 + n * 16 + lr] = acc[m][n][r];
  __syncthreads();
  int leni = length[i], lenj = length[j];
  int t = tid & 127, h = tid >> 7, s0 = h * 64;
  float mx = -1e30f;
  for (int s = s0; s < s0 + 64; ++s) {
    float vv = (s < lenj) ? S[t][s] : NEGV;
    mx = fmaxf(mx, vv);
  }
  red[t][h] = mx;
  __syncthreads();
  mx = fmaxf(red[t][0], red[t][1]);
  __syncthreads();
  float sum = 0.f;
  for (int s = s0; s < s0 + 64; ++s) {
    float vv = (s < lenj) ? S[t][s] : NEGV;
    float ee = __expf(vv - mx);
    S[t][s] = ee;
    sum += ee;
  }
  red[t][h] = sum;
  __syncthreads();
  if (h == 0) sInv[t] = (t < leni) ? 1.f / (red[t][0] + red[t][1]) : 0.f;
  __syncthreads();
  // transposed write: lwT[e][s][t], lwgT = gw[e] * lwT
  float ge = gw[e];
  int s = tid >> 1;
  int t0 = (tid & 1) * 64;
  size_t base = (size_t)e * 16384 + (size_t)s * TT;
  for (int tb = 0; tb < 64; tb += 8) {
    u16x8 w, wg;
#pragma unroll
    for (int u = 0; u < 8; ++u) {
      int tt = t0 + tb + u;
      float val = S[tt][s] * sInv[tt];
      w[u]  = f2b(val);
      wg[u] = f2b(val * ge);
    }
    *(u16x8*)(lwT  + base + t0 + tb) = w;
    *(u16x8*)(lwgT + base + t0 + tb) = wg;
  }
}

// ---------------- weighted aggregation (transpose-GEMM) ---------------------
// part[g][j][s][o] = sum_{i in group g, t} Asrc[e][s][t] * Bsrc[bidx][o][t]
// grid = (4, 16, 2): (g, j, o-half)
__global__ __launch_bounds__(256, 1)
void k_wagg(const ushort_t* __restrict__ AsrcT, const ushort_t* __restrict__ Bsrc,
            const int* __restrict__ spk, float* __restrict__ part, int mode) {
  int g = blockIdx.x, j = blockIdx.y, oh = blockIdx.z;
  WAVE_SETUP
  int R0 = wr * 64, C0 = wc * 64;
  ACC_INIT(acc)
  for (int ii = 0; ii < 4; ++ii) {
    int i = g * 4 + ii, e = i * NODES + j;
    const ushort_t* A = AsrcT + (size_t)e * 16384;
    const ushort_t* BT;
    if (mode == 1) {
      int q = spk[j] * 2 + ((i < j) ? 0 : 1);
      BT = Bsrc + (size_t)(i * 4 + q) * 32768;
    } else {
      BT = Bsrc + (size_t)i * 32768;
    }
    const ushort_t* BTo = BT + (size_t)oh * 128 * TT;
    for (int kk = 0; kk < 4; ++kk)
      wave_gemm_step(A, TT, R0, BTo, TT, C0, kk * 32 + kg * 8, lr, acc);
  }
  size_t base = (size_t)(g * NODES + j) * TT * HD + (size_t)oh * 128;
#pragma unroll
  for (int m = 0; m < 4; ++m)
#pragma unroll
    for (int n = 0; n < 4; ++n) {
      int ocol = C0 + n * 16 + lr;
#pragma unroll
      for (int r = 0; r < 4; ++r) {
        int s = R0 + m * 16 + kg * 4 + r;
        part[base + (size_t)s * HD + ocol] = acc[m][n][r];
      }
    }
}

// ---------------- reduce layer-1 partials -> x1h (bf16) + x1T (bf16) --------
// grid = (16, 2): (node j, o-half)
__global__ __launch_bounds__(256, 1)
void k_reduce1(const float* __restrict__ part, const float* __restrict__ x1part,
               ushort_t* __restrict__ x1h, ushort_t* __restrict__ x1T) {
  __shared__ ushort_t L[TT][136];
  int j = blockIdx.x, oh = blockIdx.y, tid = threadIdx.x;
  const size_t Q = (size_t)NODES * TT * HD;  // 524288 per group
  for (int p = 0; p < 16; ++p) {
    int idx = p * 256 + tid;          // 4096 float4 quads
    int t = idx >> 5, o4 = (idx & 31) * 4;
    size_t goff = ((size_t)j * TT + t) * HD + (size_t)oh * 128 + o4;
    float4 s = *(const float4*)(x1part + goff);
    for (int g = 0; g < 4; ++g) {
      float4 pv = *(const float4*)(part + (size_t)g * Q + goff);
      s.x += pv.x; s.y += pv.y; s.z += pv.z; s.w += pv.w;
    }
    u16x4 hv; hv[0] = f2b(s.x); hv[1] = f2b(s.y); hv[2] = f2b(s.z); hv[3] = f2b(s.w);
    *(u16x4*)(x1h + goff) = hv;
    *(u16x4*)(&L[t][o4]) = hv;
  }
  __syncthreads();
  for (int p = 0; p < 16; ++p) {
    int idx = p * 256 + tid;
    int o = idx >> 5, t4 = (idx & 31) * 4;
    u16x4 v;
#pragma unroll
    for (int u = 0; u < 4; ++u) v[u] = L[t4 + u][o];
    *(u16x4*)(x1T + (size_t)j * 32768 + (size_t)(oh * 128 + o) * TT + t4) = v;
  }
}

// ---------------- reduce layer-2 partials -> Z2h (bf16, row-major) ----------
__global__ void k_reduce2(const float* __restrict__ part, ushort_t* __restrict__ Z2h) {
  int idx = blockIdx.x * 256 + threadIdx.x;  // 131072 quads
  size_t o4 = (size_t)idx * 4;
  const size_t Q = (size_t)NODES * TT * HD;
  float4 s = *(const float4*)(part + o4);
  for (int g = 1; g < 4; ++g) {
    float4 pv = *(const float4*)(part + (size_t)g * Q + o4);
    s.x += pv.x; s.y += pv.y; s.z += pv.z; s.w += pv.w;
  }
  u16x4 hv; hv[0] = f2b(s.x); hv[1] = f2b(s.y); hv[2] = f2b(s.z); hv[3] = f2b(s.w);
  *(u16x4*)(Z2h + o4) = hv;
}

// ---------------- out = Z2h @ Wrel2 + x1h @ Wroot2 + b2 (f32) ---------------
__global__ __launch_bounds__(256, 1)
void k_final(const ushort_t* __restrict__ Z2h, const ushort_t* __restrict__ Wrel2T,
             const ushort_t* __restrict__ x1h, const ushort_t* __restrict__ Wroot2T,
             const float* __restrict__ b2, float* __restrict__ out) {
  WAVE_SETUP
  int R0 = blockIdx.x * 128 + wr * 64, C0 = blockIdx.y * 128 + wc * 64;
  ACC_INIT(acc)
  for (int kk = 0; kk < 8; ++kk)
    wave_gemm_step(Z2h, HD, R0, Wrel2T, HD, C0, kk * 32 + kg * 8, lr, acc);
  for (int kk = 0; kk < 8; ++kk)
    wave_gemm_step(x1h, HD, R0, Wroot2T, HD, C0, kk * 32 + kg * 8, lr, acc);
#pragma unroll
  for (int m = 0; m < 4; ++m)
#pragma unroll
    for (int n = 0; n < 4; ++n) {
      int col = C0 + n * 16 + lr;
      float bb = b2[col];
#pragma unroll
      for (int r = 0; r < 4; ++r) {
        int row = R0 + m * 16 + kg * 4 + r;
        out[(size_t)row * HD + col] = acc[m][n][r] + bb;
      }
    }
}

extern "C" void kernel_launch(void* const* d_in, const int* in_sizes, int n_in,
                              void* d_out, int out_size, void* d_ws, size_t ws_size,
                              hipStream_t stream) {
  (void)in_sizes; (void)n_in; (void)out_size; (void)ws_size;
  const float* G      = (const float*)d_in[0];
  const float* Lf     = (const float*)d_in[1];
  const int*   spk    = (const int*)d_in[2];
  const int*   len    = (const int*)d_in[3];
  const float* Wq     = (const float*)d_in[4];
  const float* Wk     = (const float*)d_in[5];
  const float* vatt   = (const float*)d_in[6];
  const float* Wb1    = (const float*)d_in[7];
  const float* Wb2    = (const float*)d_in[8];
  const float* Wrel1  = (const float*)d_in[9];
  const float* Wroot1 = (const float*)d_in[10];
  const float* b1     = (const float*)d_in[11];
  const float* Wrel2  = (const float*)d_in[12];
  const float* Wroot2 = (const float*)d_in[13];
  const float* b2     = (const float*)d_in[14];

  char* ws = (char*)d_ws;
  const size_t MB = 1ull << 20;
  float*    gw      = (float*)(ws);
  ushort_t* Lfh     = (ushort_t*)(ws + 1 * MB);
  ushort_t* Wb1T    = (ushort_t*)(ws + 2 * MB);
  ushort_t* Wb2T    = (ushort_t*)(ws + 2 * MB + 64 * 1024);
  ushort_t* Wroot1T = (ushort_t*)(ws + 2 * MB + 128 * 1024);
  ushort_t* Wroot2T = (ushort_t*)(ws + 2 * MB + 256 * 1024);
  ushort_t* Wrel2T  = (ushort_t*)(ws + 2 * MB + 384 * 1024);
  ushort_t* Wrel1T8 = (ushort_t*)(ws + 2 * MB + 512 * 1024);  // 1 MB
  ushort_t* p1h     = (ushort_t*)(ws + 4 * MB);
  ushort_t* p2h     = (ushort_t*)(ws + 4 * MB + 512 * 1024);
  ushort_t* lwT     = (ushort_t*)(ws + 5 * MB);    // 8 MB
  ushort_t* lwgT    = (ushort_t*)(ws + 13 * MB);   // 8 MB
  ushort_t* YT      = (ushort_t*)(ws + 21 * MB);   // 4 MB
  float*    x1part  = (float*)(ws + 25 * MB);      // 2 MB
  float*    part    = (float*)(ws + 27 * MB);      // 8 MB
  ushort_t* x1h     = (ushort_t*)(ws + 35 * MB);   // 1 MB
  ushort_t* x1T     = (ushort_t*)(ws + 36 * MB);   // 1 MB
  ushort_t* Z2h     = (ushort_t*)(ws + 37 * MB);   // 1 MB
  float* out = (float*)d_out;

  // prep
  k_cast_lf<<<256, 256, 0, stream>>>(Lf, Lfh);
  k_transW<<<192, 256, 0, stream>>>(Wb1, Wb2, Wroot1, Wroot2, Wrel2, Wrel1,
                                    Wb1T, Wb2T, Wroot1T, Wroot2T, Wrel2T, Wrel1T8);
  k_global_att<<<1, 256, 0, stream>>>(G, Wq, Wk, vatt, gw);
  // projections & independent GEMMs
  k_proj<<<dim3(16, 2), 256, 0, stream>>>(Lfh, Wb1T, Wb2T, p1h, p2h);
  k_x1root<<<dim3(16, 2), 256, 0, stream>>>(Lfh, Wroot1T, b1, x1part);
  k_y<<<dim3(64, 2), 256, 0, stream>>>(Lfh, Wrel1T8, spk, YT);
  // local attention
  k_locatt<<<256, 256, 0, stream>>>(p1h, p2h, len, gw, lwT, lwgT);
  // layer 1 aggregation
  k_wagg<<<dim3(4, 16, 2), 256, 0, stream>>>(lwgT, YT, spk, part, 1);
  k_reduce1<<<dim3(16, 2), 256, 0, stream>>>(part, x1part, x1h, x1T);
  // layer 2 aggregation
  k_wagg<<<dim3(4, 16, 2), 256, 0, stream>>>(lwT, x1T, spk, part, 2);
  k_reduce2<<<512, 256, 0, stream>>>(part, Z2h);
  // final fused output GEMM
  k_final<<<dim3(16, 2), 256, 0, stream>>>(Z2h, Wrel2T, x1h, Wroot2T, b2, out);
}

// Round 4
// 147.709 us; speedup vs baseline: 7.6127x; 1.3946x over previous
//
#include <hip/hip_runtime.h>

#define NODES 16
#define TT    128   // tokens per utterance
#define DIM   256   // local feature dim
#define ATTD  128   // attention inner dim
#define HD    256   // hidden dim
#define NEGV  -1e9f

typedef short bf16x8 __attribute__((ext_vector_type(8)));
typedef float f32x4  __attribute__((ext_vector_type(4)));
typedef unsigned short ushort_t;
typedef ushort_t u16x4 __attribute__((ext_vector_type(4)));
typedef ushort_t u16x8 __attribute__((ext_vector_type(8)));

__device__ __forceinline__ ushort_t f2b(float f) {
  union { float f; unsigned u; } v; v.f = f;
  unsigned r = (v.u + 0x7fffu + ((v.u >> 16) & 1u)) >> 16;
  return (ushort_t)r;
}

// one K=32 step of a 64x64 wave-tile GEMM; A row-major [.,as], BT row-major [.,bs]
__device__ __forceinline__ void wave_gemm_step(const ushort_t* __restrict__ A, int as, int R0,
                                               const ushort_t* __restrict__ BT, int bs, int C0,
                                               int kb, int lr, f32x4 acc[4][4]) {
  bf16x8 a[4], b[4];
#pragma unroll
  for (int m = 0; m < 4; ++m)
    a[m] = *(const bf16x8*)(A + (size_t)(R0 + m * 16 + lr) * as + kb);
#pragma unroll
  for (int n = 0; n < 4; ++n)
    b[n] = *(const bf16x8*)(BT + (size_t)(C0 + n * 16 + lr) * bs + kb);
#pragma unroll
  for (int m = 0; m < 4; ++m)
#pragma unroll
    for (int n = 0; n < 4; ++n)
      acc[m][n] = __builtin_amdgcn_mfma_f32_16x16x32_bf16(a[m], b[n], acc[m][n], 0, 0, 0);
}

#define WAVE_SETUP                                    \
  int tid = threadIdx.x;                              \
  int wave = tid >> 6, lane = tid & 63;               \
  int wr = wave >> 1, wc = wave & 1;                  \
  int lr = lane & 15, kg = lane >> 4;                 \
  (void)wr; (void)wc;

#define ACC_INIT(acc)                                 \
  f32x4 acc[4][4];                                    \
  { f32x4 z = {0.f, 0.f, 0.f, 0.f};                   \
    _Pragma("unroll") for (int m = 0; m < 4; ++m)     \
    _Pragma("unroll") for (int n = 0; n < 4; ++n) acc[m][n] = z; }

// ---------------- prep: cast local_features to bf16 -------------------------
__global__ void k_cast_lf(const float* __restrict__ Lf, ushort_t* __restrict__ Lfh) {
  int gi = blockIdx.x * 256 + threadIdx.x;  // 65536 threads x 8 elems
  const float4* src = (const float4*)Lf;
  float4 v0 = src[gi * 2], v1 = src[gi * 2 + 1];
  u16x8 o;
  o[0] = f2b(v0.x); o[1] = f2b(v0.y); o[2] = f2b(v0.z); o[3] = f2b(v0.w);
  o[4] = f2b(v1.x); o[5] = f2b(v1.y); o[6] = f2b(v1.z); o[7] = f2b(v1.w);
  *(u16x8*)(Lfh + (size_t)gi * 8) = o;
}

// ---------------- prep: cast+transpose all weight matrices ------------------
// grid = 192 blocks; 64x64 tiles through LDS.
__global__ void k_transW(const float* __restrict__ Wb1, const float* __restrict__ Wb2,
                         const float* __restrict__ Wroot1, const float* __restrict__ Wroot2,
                         const float* __restrict__ Wrel2, const float* __restrict__ Wrel1,
                         ushort_t* __restrict__ Wb1T, ushort_t* __restrict__ Wb2T,
                         ushort_t* __restrict__ Wroot1T, ushort_t* __restrict__ Wroot2T,
                         ushort_t* __restrict__ Wrel2T, ushort_t* __restrict__ Wrel1T8) {
  __shared__ float lds[64][65];
  int b = blockIdx.x;
  const float* src; ushort_t* dst; int R, C, t;
  if (b < 8)       { src = Wb1;    dst = Wb1T;    R = 256; C = 128; t = b; }
  else if (b < 16) { src = Wb2;    dst = Wb2T;    R = 256; C = 128; t = b - 8; }
  else if (b < 32) { src = Wroot1; dst = Wroot1T; R = 256; C = 256; t = b - 16; }
  else if (b < 48) { src = Wroot2; dst = Wroot2T; R = 256; C = 256; t = b - 32; }
  else if (b < 64) { src = Wrel2;  dst = Wrel2T;  R = 256; C = 256; t = b - 48; }
  else {
    int m = (b - 64) >> 4;                 // 0..7 -> spk_i*4 + q
    int relid = (m >> 2) * 32 + (m & 3);   // (spk_i*16 + spk_j)*2 + dir
    src = Wrel1 + (size_t)relid * 65536;
    dst = Wrel1T8 + (size_t)m * 65536;
    R = 256; C = 256; t = (b - 64) & 15;
  }
  int tilesC = C >> 6;
  int r0 = (t / tilesC) * 64, c0 = (t % tilesC) * 64;
  int tid = threadIdx.x;
  for (int p = 0; p < 16; ++p) {
    int idx = p * 256 + tid, rr = idx >> 6, cc = idx & 63;
    lds[rr][cc] = src[(size_t)(r0 + rr) * C + c0 + cc];
  }
  __syncthreads();
  for (int p = 0; p < 16; ++p) {
    int idx = p * 256 + tid, rr = idx >> 6, cc = idx & 63;
    dst[(size_t)(c0 + rr) * R + r0 + cc] = f2b(lds[cc][rr]);
  }
}

// ---------------- global attention part A: q/k projections ------------------
// grid = 16 (node i), 256 threads: t<128 -> q[i][a], t>=128 -> k[i][a]
__global__ void k_qk(const float* __restrict__ G, const float* __restrict__ Wq,
                     const float* __restrict__ Wk, float* __restrict__ qk) {
  int i = blockIdx.x, t = threadIdx.x;
  const float* W = (t < 128) ? Wq : Wk;
  int a = t & 127;
  float acc = 0.f;
#pragma unroll 8
  for (int d = 0; d < DIM; ++d)
    acc = fmaf(G[i * DIM + d], W[d * ATTD + a], acc);
  int dst = (t < 128) ? i : (NODES + i);
  qk[(size_t)dst * ATTD + a] = acc;
}

// ---------------- global attention part B: scores + softmax -> gw -----------
// grid = 16 (query i), 256 threads = 16 j x 16 a-groups (8 a's each)
__global__ void k_score(const float* __restrict__ qk, const float* __restrict__ vatt,
                        float* __restrict__ gw) {
  __shared__ float sred[NODES][17];
  __shared__ float q[ATTD];
  int i = blockIdx.x, t = threadIdx.x;
  int j = t >> 4, ag = t & 15;
  if (t < ATTD) q[t] = qk[(size_t)i * ATTD + t];
  __syncthreads();
  float sum = 0.f;
#pragma unroll
  for (int u = 0; u < 8; ++u) {
    int a = ag * 8 + u;
    sum += tanhf(q[a] + qk[(size_t)(NODES + j) * ATTD + a]) * vatt[a];
  }
  sred[j][ag] = sum;
  __syncthreads();
  if (t < NODES) {
    float s = 0.f;
#pragma unroll
    for (int u = 0; u < 16; ++u) s += sred[t][u];
    sred[t][16] = s;
  }
  __syncthreads();
  if (t == 0) {
    float m = -1e30f;
    for (int jj = 0; jj < NODES; ++jj) m = fmaxf(m, sred[jj][16]);
    float ex[NODES], ssum = 0.f;
    for (int jj = 0; jj < NODES; ++jj) { ex[jj] = __expf(sred[jj][16] - m); ssum += ex[jj]; }
    float inv = 1.f / ssum;
    for (int jj = 0; jj < NODES; ++jj) gw[i * NODES + jj] = ex[jj] * inv;
  }
}

// ---------------- p1/p2 = Lfh @ Wb{1,2}  -> bf16 [2048][128] ----------------
// grid = (16, 2): y selects which projection.
__global__ __launch_bounds__(256, 1)
void k_proj(const ushort_t* __restrict__ Lfh, const ushort_t* __restrict__ Wb1T,
            const ushort_t* __restrict__ Wb2T, ushort_t* __restrict__ p1h,
            ushort_t* __restrict__ p2h) {
  const ushort_t* BT = blockIdx.y ? Wb2T : Wb1T;
  ushort_t* out = blockIdx.y ? p2h : p1h;
  WAVE_SETUP
  int R0 = blockIdx.x * 128 + wr * 64, C0 = wc * 64;
  ACC_INIT(acc)
  for (int kk = 0; kk < 8; ++kk)
    wave_gemm_step(Lfh, DIM, R0, BT, DIM, C0, kk * 32 + kg * 8, lr, acc);
#pragma unroll
  for (int m = 0; m < 4; ++m)
#pragma unroll
    for (int n = 0; n < 4; ++n) {
      int col = C0 + n * 16 + lr;
#pragma unroll
      for (int r = 0; r < 4; ++r) {
        int row = R0 + m * 16 + kg * 4 + r;
        out[(size_t)row * ATTD + col] = f2b(acc[m][n][r]);
      }
    }
}

// ---------------- x1part = Lfh @ Wroot1 + b1 -> f32 [2048][256] -------------
__global__ __launch_bounds__(256, 1)
void k_x1root(const ushort_t* __restrict__ Lfh, const ushort_t* __restrict__ Wroot1T,
              const float* __restrict__ b1, float* __restrict__ x1part) {
  WAVE_SETUP
  int R0 = blockIdx.x * 128 + wr * 64, C0 = blockIdx.y * 128 + wc * 64;
  ACC_INIT(acc)
  for (int kk = 0; kk < 8; ++kk)
    wave_gemm_step(Lfh, DIM, R0, Wroot1T, DIM, C0, kk * 32 + kg * 8, lr, acc);
#pragma unroll
  for (int m = 0; m < 4; ++m)
#pragma unroll
    for (int n = 0; n < 4; ++n) {
      int col = C0 + n * 16 + lr;
      float bb = b1[col];
#pragma unroll
      for (int r = 0; r < 4; ++r) {
        int row = R0 + m * 16 + kg * 4 + r;
        x1part[(size_t)row * HD + col] = acc[m][n][r] + bb;
      }
    }
}

// ---------------- YT[iq][o][t] = (Lfh[i] @ Wrel1[rel])^T, bf16 --------------
// grid = (64, 2)
__global__ __launch_bounds__(256, 1)
void k_y(const ushort_t* __restrict__ Lfh, const ushort_t* __restrict__ Wrel1T8,
         const int* __restrict__ spk, ushort_t* __restrict__ YT) {
  int iq = blockIdx.x;
  int i = iq >> 2, q = iq & 3;
  int m8 = spk[i] * 4 + q;
  const ushort_t* A  = Lfh + (size_t)i * TT * DIM;
  const ushort_t* BT = Wrel1T8 + (size_t)m8 * 65536;
  WAVE_SETUP
  int R0 = wr * 64, C0 = blockIdx.y * 128 + wc * 64;
  ACC_INIT(acc)
  for (int kk = 0; kk < 8; ++kk)
    wave_gemm_step(A, DIM, R0, BT, DIM, C0, kk * 32 + kg * 8, lr, acc);
#pragma unroll
  for (int m = 0; m < 4; ++m)
#pragma unroll
    for (int n = 0; n < 4; ++n) {
      int o = C0 + n * 16 + lr;
      int t0 = R0 + m * 16 + kg * 4;
      u16x4 v;
#pragma unroll
      for (int r = 0; r < 4; ++r) v[r] = f2b(acc[m][n][r]);
      *(u16x4*)(YT + (size_t)iq * 32768 + (size_t)o * TT + t0) = v;
    }
}

// ---------------- per-edge local attention -> lwT, lwgT (bf16) --------------
// grid = 256 blocks (one per edge)
__global__ __launch_bounds__(256, 1)
void k_locatt(const ushort_t* __restrict__ p1h, const ushort_t* __restrict__ p2h,
              const int* __restrict__ length, const float* __restrict__ gw,
              ushort_t* __restrict__ lwT, ushort_t* __restrict__ lwgT) {
  __shared__ float S[TT][130];
  __shared__ float red[TT][2];
  __shared__ float sInv[TT];
  int e = blockIdx.x, i = e >> 4, j = e & 15;
  WAVE_SETUP
  int R0 = wr * 64, C0 = wc * 64;
  const ushort_t* A = p1h + (size_t)i * TT * ATTD;
  const ushort_t* B = p2h + (size_t)j * TT * ATTD;  // BT of p2^T is p2 itself
  ACC_INIT(acc)
  for (int kk = 0; kk < 4; ++kk)
    wave_gemm_step(A, ATTD, R0, B, ATTD, C0, kk * 32 + kg * 8, lr, acc);
#pragma unroll
  for (int m = 0; m < 4; ++m)
#pragma unroll
    for (int n = 0; n < 4; ++n)
#pragma unroll
      for (int r = 0; r < 4; ++r)
        S[R0 + m * 16 + kg * 4 + r][C0 + n * 16 + lr] = acc[m][n][r];
  __syncthreads();
  int leni = length[i], lenj = length[j];
  int t = tid & 127, h = tid >> 7, s0 = h * 64;
  float mx = -1e30f;
  for (int s = s0; s < s0 + 64; ++s) {
    float vv = (s < lenj) ? S[t][s] : NEGV;
    mx = fmaxf(mx, vv);
  }
  red[t][h] = mx;
  __syncthreads();
  mx = fmaxf(red[t][0], red[t][1]);
  __syncthreads();
  float sum = 0.f;
  for (int s = s0; s < s0 + 64; ++s) {
    float vv = (s < lenj) ? S[t][s] : NEGV;
    float ee = __expf(vv - mx);
    S[t][s] = ee;
    sum += ee;
  }
  red[t][h] = sum;
  __syncthreads();
  if (h == 0) sInv[t] = (t < leni) ? 1.f / (red[t][0] + red[t][1]) : 0.f;
  __syncthreads();
  // transposed write: lwT[e][s][t], lwgT = gw[e] * lwT
  float ge = gw[e];
  int s = tid >> 1;
  int t0 = (tid & 1) * 64;
  size_t base = (size_t)e * 16384 + (size_t)s * TT;
  for (int tb = 0; tb < 64; tb += 8) {
    u16x8 w, wg;
#pragma unroll
    for (int u = 0; u < 8; ++u) {
      int tt = t0 + tb + u;
      float val = S[tt][s] * sInv[tt];
      w[u]  = f2b(val);
      wg[u] = f2b(val * ge);
    }
    *(u16x8*)(lwT  + base + t0 + tb) = w;
    *(u16x8*)(lwgT + base + t0 + tb) = wg;
  }
}

// ---------------- weighted aggregation (transpose-GEMM) ---------------------
// part[g][j][s][o] = sum_{i in group g, t} Asrc[e][s][t] * Bsrc[bidx][o][t]
// grid = (4, 16, 2): (g, j, o-half)
__global__ __launch_bounds__(256, 1)
void k_wagg(const ushort_t* __restrict__ AsrcT, const ushort_t* __restrict__ Bsrc,
            const int* __restrict__ spk, float* __restrict__ part, int mode) {
  int g = blockIdx.x, j = blockIdx.y, oh = blockIdx.z;
  WAVE_SETUP
  int R0 = wr * 64, C0 = wc * 64;
  ACC_INIT(acc)
  for (int ii = 0; ii < 4; ++ii) {
    int i = g * 4 + ii, e = i * NODES + j;
    const ushort_t* A = AsrcT + (size_t)e * 16384;
    const ushort_t* BT;
    if (mode == 1) {
      int q = spk[j] * 2 + ((i < j) ? 0 : 1);
      BT = Bsrc + (size_t)(i * 4 + q) * 32768;
    } else {
      BT = Bsrc + (size_t)i * 32768;
    }
    const ushort_t* BTo = BT + (size_t)oh * 128 * TT;
    for (int kk = 0; kk < 4; ++kk)
      wave_gemm_step(A, TT, R0, BTo, TT, C0, kk * 32 + kg * 8, lr, acc);
  }
  size_t base = (size_t)(g * NODES + j) * TT * HD + (size_t)oh * 128;
#pragma unroll
  for (int m = 0; m < 4; ++m)
#pragma unroll
    for (int n = 0; n < 4; ++n) {
      int ocol = C0 + n * 16 + lr;
#pragma unroll
      for (int r = 0; r < 4; ++r) {
        int s = R0 + m * 16 + kg * 4 + r;
        part[base + (size_t)s * HD + ocol] = acc[m][n][r];
      }
    }
}

// ---------------- reduce layer-1 partials -> x1h (bf16) + x1T (bf16) --------
// grid = (16, 2): (node j, o-half)
__global__ __launch_bounds__(256, 1)
void k_reduce1(const float* __restrict__ part, const float* __restrict__ x1part,
               ushort_t* __restrict__ x1h, ushort_t* __restrict__ x1T) {
  __shared__ ushort_t L[TT][136];
  int j = blockIdx.x, oh = blockIdx.y, tid = threadIdx.x;
  const size_t Q = (size_t)NODES * TT * HD;  // 524288 per group
  for (int p = 0; p < 16; ++p) {
    int idx = p * 256 + tid;          // 4096 float4 quads
    int t = idx >> 5, o4 = (idx & 31) * 4;
    size_t goff = ((size_t)j * TT + t) * HD + (size_t)oh * 128 + o4;
    float4 s = *(const float4*)(x1part + goff);
    for (int g = 0; g < 4; ++g) {
      float4 pv = *(const float4*)(part + (size_t)g * Q + goff);
      s.x += pv.x; s.y += pv.y; s.z += pv.z; s.w += pv.w;
    }
    u16x4 hv; hv[0] = f2b(s.x); hv[1] = f2b(s.y); hv[2] = f2b(s.z); hv[3] = f2b(s.w);
    *(u16x4*)(x1h + goff) = hv;
    *(u16x4*)(&L[t][o4]) = hv;
  }
  __syncthreads();
  for (int p = 0; p < 16; ++p) {
    int idx = p * 256 + tid;
    int o = idx >> 5, t4 = (idx & 31) * 4;
    u16x4 v;
#pragma unroll
    for (int u = 0; u < 4; ++u) v[u] = L[t4 + u][o];
    *(u16x4*)(x1T + (size_t)j * 32768 + (size_t)(oh * 128 + o) * TT + t4) = v;
  }
}

// ---------------- reduce layer-2 partials -> Z2h (bf16, row-major) ----------
__global__ void k_reduce2(const float* __restrict__ part, ushort_t* __restrict__ Z2h) {
  int idx = blockIdx.x * 256 + threadIdx.x;  // 131072 quads
  size_t o4 = (size_t)idx * 4;
  const size_t Q = (size_t)NODES * TT * HD;
  float4 s = *(const float4*)(part + o4);
  for (int g = 1; g < 4; ++g) {
    float4 pv = *(const float4*)(part + (size_t)g * Q + o4);
    s.x += pv.x; s.y += pv.y; s.z += pv.z; s.w += pv.w;
  }
  u16x4 hv; hv[0] = f2b(s.x); hv[1] = f2b(s.y); hv[2] = f2b(s.z); hv[3] = f2b(s.w);
  *(u16x4*)(Z2h + o4) = hv;
}

// ---------------- out = Z2h @ Wrel2 + x1h @ Wroot2 + b2 (f32) ---------------
__global__ __launch_bounds__(256, 1)
void k_final(const ushort_t* __restrict__ Z2h, const ushort_t* __restrict__ Wrel2T,
             const ushort_t* __restrict__ x1h, const ushort_t* __restrict__ Wroot2T,
             const float* __restrict__ b2, float* __restrict__ out) {
  WAVE_SETUP
  int R0 = blockIdx.x * 128 + wr * 64, C0 = blockIdx.y * 128 + wc * 64;
  ACC_INIT(acc)
  for (int kk = 0; kk < 8; ++kk)
    wave_gemm_step(Z2h, HD, R0, Wrel2T, HD, C0, kk * 32 + kg * 8, lr, acc);
  for (int kk = 0; kk < 8; ++kk)
    wave_gemm_step(x1h, HD, R0, Wroot2T, HD, C0, kk * 32 + kg * 8, lr, acc);
#pragma unroll
  for (int m = 0; m < 4; ++m)
#pragma unroll
    for (int n = 0; n < 4; ++n) {
      int col = C0 + n * 16 + lr;
      float bb = b2[col];
#pragma unroll
      for (int r = 0; r < 4; ++r) {
        int row = R0 + m * 16 + kg * 4 + r;
        out[(size_t)row * HD + col] = acc[m][n][r] + bb;
      }
    }
}

extern "C" void kernel_launch(void* const* d_in, const int* in_sizes, int n_in,
                              void* d_out, int out_size, void* d_ws, size_t ws_size,
                              hipStream_t stream) {
  (void)in_sizes; (void)n_in; (void)out_size; (void)ws_size;
  const float* G      = (const float*)d_in[0];
  const float* Lf     = (const float*)d_in[1];
  const int*   spk    = (const int*)d_in[2];
  const int*   len    = (const int*)d_in[3];
  const float* Wq     = (const float*)d_in[4];
  const float* Wk     = (const float*)d_in[5];
  const float* vatt   = (const float*)d_in[6];
  const float* Wb1    = (const float*)d_in[7];
  const float* Wb2    = (const float*)d_in[8];
  const float* Wrel1  = (const float*)d_in[9];
  const float* Wroot1 = (const float*)d_in[10];
  const float* b1     = (const float*)d_in[11];
  const float* Wrel2  = (const float*)d_in[12];
  const float* Wroot2 = (const float*)d_in[13];
  const float* b2     = (const float*)d_in[14];

  char* ws = (char*)d_ws;
  const size_t MB = 1ull << 20;
  float*    gw      = (float*)(ws);
  float*    qk      = (float*)(ws + 16 * 1024);
  ushort_t* Lfh     = (ushort_t*)(ws + 1 * MB);
  ushort_t* Wb1T    = (ushort_t*)(ws + 2 * MB);
  ushort_t* Wb2T    = (ushort_t*)(ws + 2 * MB + 64 * 1024);
  ushort_t* Wroot1T = (ushort_t*)(ws + 2 * MB + 128 * 1024);
  ushort_t* Wroot2T = (ushort_t*)(ws + 2 * MB + 256 * 1024);
  ushort_t* Wrel2T  = (ushort_t*)(ws + 2 * MB + 384 * 1024);
  ushort_t* Wrel1T8 = (ushort_t*)(ws + 2 * MB + 512 * 1024);  // 1 MB
  ushort_t* p1h     = (ushort_t*)(ws + 4 * MB);
  ushort_t* p2h     = (ushort_t*)(ws + 4 * MB + 512 * 1024);
  ushort_t* lwT     = (ushort_t*)(ws + 5 * MB);    // 8 MB
  ushort_t* lwgT    = (ushort_t*)(ws + 13 * MB);   // 8 MB
  ushort_t* YT      = (ushort_t*)(ws + 21 * MB);   // 4 MB
  float*    x1part  = (float*)(ws + 25 * MB);      // 2 MB
  float*    part    = (float*)(ws + 27 * MB);      // 8 MB
  ushort_t* x1h     = (ushort_t*)(ws + 35 * MB);   // 1 MB
  ushort_t* x1T     = (ushort_t*)(ws + 36 * MB);   // 1 MB
  ushort_t* Z2h     = (ushort_t*)(ws + 37 * MB);   // 1 MB
  float* out = (float*)d_out;

  // prep
  k_cast_lf<<<256, 256, 0, stream>>>(Lf, Lfh);
  k_transW<<<192, 256, 0, stream>>>(Wb1, Wb2, Wroot1, Wroot2, Wrel2, Wrel1,
                                    Wb1T, Wb2T, Wroot1T, Wroot2T, Wrel2T, Wrel1T8);
  // global attention (parallelized)
  k_qk<<<16, 256, 0, stream>>>(G, Wq, Wk, qk);
  k_score<<<16, 256, 0, stream>>>(qk, vatt, gw);
  // projections & independent GEMMs
  k_proj<<<dim3(16, 2), 256, 0, stream>>>(Lfh, Wb1T, Wb2T, p1h, p2h);
  k_x1root<<<dim3(16, 2), 256, 0, stream>>>(Lfh, Wroot1T, b1, x1part);
  k_y<<<dim3(64, 2), 256, 0, stream>>>(Lfh, Wrel1T8, spk, YT);
  // local attention
  k_locatt<<<256, 256, 0, stream>>>(p1h, p2h, len, gw, lwT, lwgT);
  // layer 1 aggregation
  k_wagg<<<dim3(4, 16, 2), 256, 0, stream>>>(lwgT, YT, spk, part, 1);
  k_reduce1<<<dim3(16, 2), 256, 0, stream>>>(part, x1part, x1h, x1T);
  // layer 2 aggregation
  k_wagg<<<dim3(4, 16, 2), 256, 0, stream>>>(lwT, x1T, spk, part, 2);
  k_reduce2<<<512, 256, 0, stream>>>(part, Z2h);
  // final fused output GEMM
  k_final<<<dim3(16, 2), 256, 0, stream>>>(Z2h, Wrel2T, x1h, Wroot2T, b2, out);
}